// Round 2
// baseline (12683.069 us; speedup 1.0000x reference)
//
#include <hip/hip_runtime.h>
#include <hip/hip_bf16.h>

// LSTM fused persistent kernel for MI355X (gfx950).
// B=64, T=1024, D=512, H=512. One kernel, 64 blocks x 256 threads.
// Sync redesign: 4 independent per-batch-row-group pipelines (one per wave
// slot), per-wave epoch flags (128B apart), RELEASE publish + lane-parallel
// ACQUIRE polling. No grid barrier, no __syncthreads in the t-loop.

#define BB   64
#define TT   1024
#define DD   512
#define HH   512
#define NBLK 64
#define JPB  8      // h-columns owned per block
#define NTHR 256    // 4 waves
#define FSTR 32     // ints per flag slot (128 B)

typedef float  f32x4  __attribute__((ext_vector_type(4)));
typedef __bf16 bf16x8 __attribute__((ext_vector_type(8)));
typedef __bf16 bf16x4 __attribute__((ext_vector_type(4)));

__device__ __forceinline__ float sigf(float v)   { return 1.f / (1.f + __expf(-v)); }
__device__ __forceinline__ float tanh_f(float v) { return 2.f / (1.f + __expf(-2.f * v)) - 1.f; }

__global__ __launch_bounds__(NTHR) void lstm_fused(
    const float* __restrict__ x,
    const float* __restrict__ Wc, const float* __restrict__ Wi,
    const float* __restrict__ Wf, const float* __restrict__ Wo,
    const float* __restrict__ Uc, const float* __restrict__ Ui,
    const float* __restrict__ Uf, const float* __restrict__ Uo,
    const float* __restrict__ bc, const float* __restrict__ bi,
    const float* __restrict__ bfv, const float* __restrict__ bo,
    float* __restrict__ out,
    __bf16* hb0, __bf16* hb1, int* flags, __bf16* xbf, int use_xbf)
{
  // WU[n][k]: n in [0,32) gate-col (gate = n&3, jloc = n>>2), k in [0,1024):
  // k<512 -> W_gate[k][j], else U_gate[k-512][j]. bf16, 64 KiB, XOR-swizzled.
  __shared__ __bf16 WU[32 * 1024];

  const int tid = threadIdx.x;
  const int w   = tid >> 6;      // wave id = batch-row group
  const int l   = tid & 63;
  const int l15 = l & 15;
  const int l4  = l >> 4;
  const int g   = blockIdx.x;
  const int j0  = g * JPB;

  // ---- one-time: stage W/U slice into LDS (block-cooperative) ----
  for (int idx = tid; idx < 32 * 1024; idx += NTHR) {
    int n = idx & 31;
    int k = idx >> 5;
    int gg = n & 3;
    int j = j0 + (n >> 2);
    const float* Wg = (gg == 0) ? Wc : (gg == 1) ? Wi : (gg == 2) ? Wf : Wo;
    const float* Ug = (gg == 0) ? Uc : (gg == 1) ? Ui : (gg == 2) ? Uf : Uo;
    float v = (k < DD) ? Wg[k * HH + j] : Ug[(k - DD) * HH + j];
    int off = ((n << 11) + (k << 1)) ^ ((n & 7) << 4);
    *reinterpret_cast<__bf16*>(reinterpret_cast<char*>(WU) + off) = (__bf16)v;
  }
  __syncthreads();   // WU visible to all waves of this block

  // ---- one-time: cast x rows [16w,16w+16) slice g to bf16 ----
  // Partitioned so consumer group w only depends on flags (*, w).
  if (use_xbf) {
    const size_t base = (size_t)(w * 16) * TT * DD;
    const f32x4* xs = reinterpret_cast<const f32x4*>(x + base);
    bf16x4*      xd = reinterpret_cast<bf16x4*>(xbf + base);
    const int per = (16 * TT * DD / 4) / NBLK;   // 32768 vec4 per wave
    const int end = (g + 1) * per;
    for (int i = g * per + l; i < end; i += 64) {
      f32x4 v = xs[i];
      bf16x4 o;
      o[0] = (__bf16)v[0]; o[1] = (__bf16)v[1];
      o[2] = (__bf16)v[2]; o[3] = (__bf16)v[3];
      xd[i] = o;
    }
  }

  // publish init: flag = 1  <=>  h_state_0 (memset zeros) + my xbf slice ready
  int* myflag = flags + (g * 4 + w) * FSTR;
  if (l == 0)
    __hip_atomic_store(myflag, 1, __ATOMIC_RELEASE, __HIP_MEMORY_SCOPE_AGENT);

  // ---- per-lane constants ----
  // C-frag mapping: gate = reg idx r, jloc = mt*4 + l4, batch col = w*16+l15.
  const int brow  = w * 16 + l15;
  const int koff  = l4 * 8;
  const int baseA = (l15 << 11) + (koff << 1);
  const int swzA  = (l15 & 7) << 4;
  const char* WUc = reinterpret_cast<const char*>(WU);

  const int jA = j0 + l4;
  const int jB = jA + 4;
  const float bc0 = bc[jA], bi0 = bi[jA], bf0 = bfv[jA], bo0 = bo[jA];
  const float bc1 = bc[jB], bi1 = bi[jB], bf1 = bfv[jB], bo1 = bo[jB];

  const size_t xbase = (size_t)brow * TT * DD + koff;
  const size_t obase = (size_t)brow * TT * HH;
  const int    hbase = brow * HH + koff;
  const int    hsA   = brow * HH + jA;
  const int    hsB   = brow * HH + jB;

  const int* pf = flags + (l * 4 + w) * FSTR;   // lane l polls producer block l

  __bf16* hcur = hb0;
  __bf16* hnxt = hb1;
  float c0 = 0.f, c1 = 0.f;

  for (int t = 0; t < TT; ++t) {
    f32x4 acc0 = {0.f, 0.f, 0.f, 0.f};
    f32x4 acc1 = {0.f, 0.f, 0.f, 0.f};

    // ---- x-part (independent of h) : hidden in the wait window ----
    if (use_xbf) {
      const __bf16* xrow = xbf + xbase + (size_t)t * DD;
      #pragma unroll
      for (int kk = 0; kk < 16; ++kk) {
        bf16x8 bfr = *reinterpret_cast<const bf16x8*>(xrow + kk * 32);
        int oA = (baseA + (kk << 6)) ^ swzA;
        bf16x8 a0 = *reinterpret_cast<const bf16x8*>(WUc + oA);
        bf16x8 a1 = *reinterpret_cast<const bf16x8*>(WUc + oA + 32768);
        acc0 = __builtin_amdgcn_mfma_f32_16x16x32_bf16(a0, bfr, acc0, 0, 0, 0);
        acc1 = __builtin_amdgcn_mfma_f32_16x16x32_bf16(a1, bfr, acc1, 0, 0, 0);
      }
    } else {
      const float* xrow = x + xbase + (size_t)t * DD;
      #pragma unroll
      for (int kk = 0; kk < 16; ++kk) {
        f32x4 f0 = *reinterpret_cast<const f32x4*>(xrow + kk * 32);
        f32x4 f1 = *reinterpret_cast<const f32x4*>(xrow + kk * 32 + 4);
        bf16x8 bfr;
        bfr[0] = (__bf16)f0[0]; bfr[1] = (__bf16)f0[1];
        bfr[2] = (__bf16)f0[2]; bfr[3] = (__bf16)f0[3];
        bfr[4] = (__bf16)f1[0]; bfr[5] = (__bf16)f1[1];
        bfr[6] = (__bf16)f1[2]; bfr[7] = (__bf16)f1[3];
        int oA = (baseA + (kk << 6)) ^ swzA;
        bf16x8 a0 = *reinterpret_cast<const bf16x8*>(WUc + oA);
        bf16x8 a1 = *reinterpret_cast<const bf16x8*>(WUc + oA + 32768);
        acc0 = __builtin_amdgcn_mfma_f32_16x16x32_bf16(a0, bfr, acc0, 0, 0, 0);
        acc1 = __builtin_amdgcn_mfma_f32_16x16x32_bf16(a1, bfr, acc1, 0, 0, 0);
      }
    }

    // ---- wait for h_state_t: all group-w producer waves at flag >= t+1 ----
    const int tgt = t + 1;
    int v = __hip_atomic_load(pf, __ATOMIC_ACQUIRE, __HIP_MEMORY_SCOPE_AGENT);
    while (!__all(v >= tgt)) {
      __builtin_amdgcn_s_sleep(1);
      v = __hip_atomic_load(pf, __ATOMIC_ACQUIRE, __HIP_MEMORY_SCOPE_AGENT);
    }

    // ---- h-part ----
    {
      const __bf16* hrow = hcur + hbase;
      #pragma unroll
      for (int kk = 0; kk < 16; ++kk) {
        bf16x8 bfr = *reinterpret_cast<const bf16x8*>(hrow + kk * 32);
        int oA = (baseA + 1024 + (kk << 6)) ^ swzA;
        bf16x8 a0 = *reinterpret_cast<const bf16x8*>(WUc + oA);
        bf16x8 a1 = *reinterpret_cast<const bf16x8*>(WUc + oA + 32768);
        acc0 = __builtin_amdgcn_mfma_f32_16x16x32_bf16(a0, bfr, acc0, 0, 0, 0);
        acc1 = __builtin_amdgcn_mfma_f32_16x16x32_bf16(a1, bfr, acc1, 0, 0, 0);
      }
    }

    // ---- epilogue: gates -> c,h; store h slice; publish; deferred out ----
    float hA, hB;
    {
      float a = tanh_f(acc0[0] + bc0);
      float i = sigf  (acc0[1] + bi0);
      float f = sigf  (acc0[2] + bf0);
      float o = sigf  (acc0[3] + bo0);
      c0 = i * a + f * c0;
      hA = o * tanh_f(c0);
      hnxt[hsA] = (__bf16)hA;
    }
    {
      float a = tanh_f(acc1[0] + bc1);
      float i = sigf  (acc1[1] + bi1);
      float f = sigf  (acc1[2] + bf1);
      float o = sigf  (acc1[3] + bo1);
      c1 = i * a + f * c1;
      hB = o * tanh_f(c1);
      hnxt[hsB] = (__bf16)hB;
    }

    if (l == 0)
      __hip_atomic_store(myflag, t + 2, __ATOMIC_RELEASE, __HIP_MEMORY_SCOPE_AGENT);

    // out stores off the critical path (nobody reads out during the kernel)
    out[obase + (size_t)t * HH + jA] = hA;
    out[obase + (size_t)t * HH + jB] = hB;

    __bf16* tmp = hcur; hcur = hnxt; hnxt = tmp;
  }
}

extern "C" void kernel_launch(void* const* d_in, const int* in_sizes, int n_in,
                              void* d_out, int out_size, void* d_ws, size_t ws_size,
                              hipStream_t stream) {
  const float* x   = (const float*)d_in[0];
  const float* Wc  = (const float*)d_in[1];
  const float* Wi  = (const float*)d_in[2];
  const float* Wf  = (const float*)d_in[3];
  const float* Wo  = (const float*)d_in[4];
  const float* Uc  = (const float*)d_in[5];
  const float* Ui  = (const float*)d_in[6];
  const float* Uf  = (const float*)d_in[7];
  const float* Uo  = (const float*)d_in[8];
  const float* bc  = (const float*)d_in[9];
  const float* bi  = (const float*)d_in[10];
  const float* bfv = (const float*)d_in[11];
  const float* bo  = (const float*)d_in[12];
  float* out = (float*)d_out;

  char* ws = (char*)d_ws;
  __bf16* hb0   = (__bf16*)ws;                     //  65536 B
  __bf16* hb1   = (__bf16*)(ws + 65536);           //  65536 B
  int*    flags = (int*)(ws + 131072);             //  256 flags * 128 B = 32 KiB
  __bf16* xbf   = (__bf16*)(ws + 163840);          //  64 MiB optional
  const size_t need_xbf = 163840ull + (size_t)BB * TT * DD * 2ull;
  int use_xbf = (ws_size >= need_xbf) ? 1 : 0;

  size_t zbytes = 163840;                          // hb0 + hb1 + flags
  if (zbytes > ws_size) zbytes = ws_size;
  hipMemsetAsync(d_ws, 0, zbytes, stream);

  lstm_fused<<<dim3(NBLK), dim3(NTHR), 0, stream>>>(
      x, Wc, Wi, Wf, Wo, Uc, Ui, Uf, Uo, bc, bi, bfv, bo,
      out, hb0, hb1, flags, xbf, use_xbf);
}

// Round 3
// 5429.068 us; speedup vs baseline: 2.3361x; 2.3361x over previous
//
#include <hip/hip_runtime.h>
#include <hip/hip_bf16.h>

// LSTM fused persistent kernel for MI355X (gfx950).
// B=64, T=1024, D=512, H=512. 64 blocks x 256 threads, persistent.
// Cross-XCD handoff of h via explicit coherence-point (sc0 sc1) accesses;
// RELAXED flag polling (no buffer_inv/wbl2 in the hot loop).

#define BB   64
#define TT   1024
#define DD   512
#define HH   512
#define NBLK 64
#define JPB  8      // h-columns owned per block
#define NTHR 256    // 4 waves

typedef float  f32x4  __attribute__((ext_vector_type(4)));
typedef __bf16 bf16x8 __attribute__((ext_vector_type(8)));
typedef __bf16 bf16x4 __attribute__((ext_vector_type(4)));

__device__ __forceinline__ float sigf(float v)   { return 1.f / (1.f + __expf(-v)); }
__device__ __forceinline__ float tanh_f(float v) { return 2.f / (1.f + __expf(-2.f * v)) - 1.f; }

// L2-bypassing accesses serviced at the agent coherence point (L3).
// No cache-maintenance instructions => per-XCD L2 stays warm for x/xbf.
__device__ __forceinline__ f32x4 hload16(const __bf16* p) {
  f32x4 r;
  asm volatile("global_load_dwordx4 %0, %1, off sc0 sc1"
               : "=v"(r) : "v"(p) : "memory");
  return r;
}
__device__ __forceinline__ void hstore2(__bf16* p, __bf16 v) {
  unsigned short u = __builtin_bit_cast(unsigned short, v);
  asm volatile("global_store_short %0, %1, off sc0 sc1"
               :: "v"(p), "v"(u) : "memory");
}

__global__ __launch_bounds__(NTHR) void lstm_fused(
    const float* __restrict__ x,
    const float* __restrict__ Wc, const float* __restrict__ Wi,
    const float* __restrict__ Wf, const float* __restrict__ Wo,
    const float* __restrict__ Uc, const float* __restrict__ Ui,
    const float* __restrict__ Uf, const float* __restrict__ Uo,
    const float* __restrict__ bc, const float* __restrict__ bi,
    const float* __restrict__ bfv, const float* __restrict__ bo,
    float* __restrict__ out,
    __bf16* hb0, __bf16* hb1, int* flags, __bf16* xbf, int use_xbf)
{
  // WU[n][k]: n in [0,32) gate-col (gate = n&3, jloc = n>>2), k in [0,1024):
  // k<512 -> W_gate[k][j], else U_gate[k-512][j]. bf16, 64 KiB, XOR-swizzled.
  __shared__ __bf16 WU[32 * 1024];

  const int tid = threadIdx.x;
  const int w   = tid >> 6;      // wave id = batch-row group
  const int l   = tid & 63;
  const int l15 = l & 15;
  const int l4  = l >> 4;
  const int g   = blockIdx.x;
  const int j0  = g * JPB;

  // ---- one-time: stage W/U slice into LDS (block-cooperative) ----
  for (int idx = tid; idx < 32 * 1024; idx += NTHR) {
    int n = idx & 31;
    int k = idx >> 5;
    int gg = n & 3;
    int j = j0 + (n >> 2);
    const float* Wg = (gg == 0) ? Wc : (gg == 1) ? Wi : (gg == 2) ? Wf : Wo;
    const float* Ug = (gg == 0) ? Uc : (gg == 1) ? Ui : (gg == 2) ? Uf : Uo;
    float v = (k < DD) ? Wg[k * HH + j] : Ug[(k - DD) * HH + j];
    int off = ((n << 11) + (k << 1)) ^ ((n & 7) << 4);
    *reinterpret_cast<__bf16*>(reinterpret_cast<char*>(WU) + off) = (__bf16)v;
  }
  __syncthreads();

  // ---- one-time: cast x rows [16w,16w+16), slice g, to bf16 ----
  if (use_xbf) {
    const size_t base = (size_t)(w * 16) * TT * DD;
    const f32x4* xs = reinterpret_cast<const f32x4*>(x + base);
    bf16x4*      xd = reinterpret_cast<bf16x4*>(xbf + base);
    const int per = (16 * TT * DD / 4) / NBLK;
    const int end = (g + 1) * per;
    #pragma unroll 4
    for (int i = g * per + l; i < end; i += 64) {
      f32x4 v = xs[i];
      bf16x4 o;
      o[0] = (__bf16)v[0]; o[1] = (__bf16)v[1];
      o[2] = (__bf16)v[2]; o[3] = (__bf16)v[3];
      xd[i] = o;
    }
  }

  // flags[w*64 + g], 4B dense: group w occupies its own 4 cachelines.
  int* myflag = flags + w * NBLK + g;
  int* pf     = flags + w * NBLK + l;   // lane l polls producer block l

  // Init publish: RELEASE (wbl2) makes the cached xbf writes visible.
  if (l == 0)
    __hip_atomic_store(myflag, 1, __ATOMIC_RELEASE, __HIP_MEMORY_SCOPE_AGENT);
  // Init wait: ACQUIRE poll (buffer_inv per poll — only at startup).
  {
    int v = __hip_atomic_load(pf, __ATOMIC_ACQUIRE, __HIP_MEMORY_SCOPE_AGENT);
    while (!__all(v >= 1)) {
      __builtin_amdgcn_s_sleep(1);
      v = __hip_atomic_load(pf, __ATOMIC_ACQUIRE, __HIP_MEMORY_SCOPE_AGENT);
    }
  }
  __builtin_amdgcn_sched_barrier(0);

  // ---- per-lane constants ----
  const int brow  = w * 16 + l15;
  const int koff  = l4 * 8;
  const int baseA = (l15 << 11) + (koff << 1);
  const int swzA  = (l15 & 7) << 4;
  const char* WUc = reinterpret_cast<const char*>(WU);

  const int jA = j0 + l4;
  const int jB = jA + 4;
  const float bc0 = bc[jA], bi0 = bi[jA], bf0 = bfv[jA], bo0 = bo[jA];
  const float bc1 = bc[jB], bi1 = bi[jB], bf1 = bfv[jB], bo1 = bo[jB];

  const size_t xbase = (size_t)brow * TT * DD + koff;
  const int    hbase = brow * HH + koff;

  // read/write pointer triples for the double buffer (swap each step)
  const __bf16* rd_c = hb0 + hbase;          // read h_t
  const __bf16* rd_n = hb1 + hbase;
  __bf16* wA_c = hb1 + (brow * HH + jA);     // write h_{t+1} (opposite buffer)
  __bf16* wA_n = hb0 + (brow * HH + jA);
  __bf16* wB_c = hb1 + (brow * HH + jB);
  __bf16* wB_n = hb0 + (brow * HH + jB);

  const __bf16* xp  = xbf + xbase;
  const float*  xpf = x + xbase;
  float* opA = out + (size_t)brow * TT * HH + jA;
  float* opB = out + (size_t)brow * TT * HH + jB;

  float c0 = 0.f, c1 = 0.f;

  for (int t = 0; t < TT; ++t) {
    // biases folded into accumulator init (C-frag reg r = gate r)
    f32x4 acc0 = {bc0, bi0, bf0, bo0};
    f32x4 acc1 = {bc1, bi1, bf1, bo1};

    // ---- x-part (independent of h): runs before/during the wait ----
    if (use_xbf) {
      #pragma unroll
      for (int kk = 0; kk < 16; ++kk) {
        bf16x8 bfr = *reinterpret_cast<const bf16x8*>(xp + kk * 32);
        int oA = (baseA + (kk << 6)) ^ swzA;
        bf16x8 a0 = *reinterpret_cast<const bf16x8*>(WUc + oA);
        bf16x8 a1 = *reinterpret_cast<const bf16x8*>(WUc + oA + 32768);
        acc0 = __builtin_amdgcn_mfma_f32_16x16x32_bf16(a0, bfr, acc0, 0, 0, 0);
        acc1 = __builtin_amdgcn_mfma_f32_16x16x32_bf16(a1, bfr, acc1, 0, 0, 0);
      }
    } else {
      #pragma unroll
      for (int kk = 0; kk < 16; ++kk) {
        f32x4 f0 = *reinterpret_cast<const f32x4*>(xpf + kk * 32);
        f32x4 f1 = *reinterpret_cast<const f32x4*>(xpf + kk * 32 + 4);
        bf16x8 bfr;
        bfr[0] = (__bf16)f0[0]; bfr[1] = (__bf16)f0[1];
        bfr[2] = (__bf16)f0[2]; bfr[3] = (__bf16)f0[3];
        bfr[4] = (__bf16)f1[0]; bfr[5] = (__bf16)f1[1];
        bfr[6] = (__bf16)f1[2]; bfr[7] = (__bf16)f1[3];
        int oA = (baseA + (kk << 6)) ^ swzA;
        bf16x8 a0 = *reinterpret_cast<const bf16x8*>(WUc + oA);
        bf16x8 a1 = *reinterpret_cast<const bf16x8*>(WUc + oA + 32768);
        acc0 = __builtin_amdgcn_mfma_f32_16x16x32_bf16(a0, bfr, acc0, 0, 0, 0);
        acc1 = __builtin_amdgcn_mfma_f32_16x16x32_bf16(a1, bfr, acc1, 0, 0, 0);
      }
    }

    // ---- wait for h_t: RELAXED polls, no cache maintenance ----
    {
      const int tgt = t + 1;
      int v = __hip_atomic_load(pf, __ATOMIC_RELAXED, __HIP_MEMORY_SCOPE_AGENT);
      while (!__all(v >= tgt)) {
        v = __hip_atomic_load(pf, __ATOMIC_RELAXED, __HIP_MEMORY_SCOPE_AGENT);
      }
    }
    __builtin_amdgcn_sched_barrier(0);

    // ---- h-part: 16 coherent 16B loads, two-phase waitcnt ----
    f32x4 hl[16];
    #pragma unroll
    for (int kk = 0; kk < 16; ++kk) hl[kk] = hload16(rd_c + kk * 32);

    asm volatile("s_waitcnt vmcnt(8)" ::: "memory");
    __builtin_amdgcn_sched_barrier(0);
    #pragma unroll
    for (int kk = 0; kk < 8; ++kk) {
      int oA = (baseA + 1024 + (kk << 6)) ^ swzA;
      bf16x8 a0 = *reinterpret_cast<const bf16x8*>(WUc + oA);
      bf16x8 a1 = *reinterpret_cast<const bf16x8*>(WUc + oA + 32768);
      bf16x8 b  = __builtin_bit_cast(bf16x8, hl[kk]);
      acc0 = __builtin_amdgcn_mfma_f32_16x16x32_bf16(a0, b, acc0, 0, 0, 0);
      acc1 = __builtin_amdgcn_mfma_f32_16x16x32_bf16(a1, b, acc1, 0, 0, 0);
    }
    asm volatile("s_waitcnt vmcnt(0)" ::: "memory");
    __builtin_amdgcn_sched_barrier(0);
    #pragma unroll
    for (int kk = 8; kk < 16; ++kk) {
      int oA = (baseA + 1024 + (kk << 6)) ^ swzA;
      bf16x8 a0 = *reinterpret_cast<const bf16x8*>(WUc + oA);
      bf16x8 a1 = *reinterpret_cast<const bf16x8*>(WUc + oA + 32768);
      bf16x8 b  = __builtin_bit_cast(bf16x8, hl[kk]);
      acc0 = __builtin_amdgcn_mfma_f32_16x16x32_bf16(a0, b, acc0, 0, 0, 0);
      acc1 = __builtin_amdgcn_mfma_f32_16x16x32_bf16(a1, b, acc1, 0, 0, 0);
    }

    // ---- epilogue: gates -> c,h ----
    float a0v = tanh_f(acc0[0]);
    float i0v = sigf  (acc0[1]);
    float f0v = sigf  (acc0[2]);
    float o0v = sigf  (acc0[3]);
    c0 = i0v * a0v + f0v * c0;
    float hA = o0v * tanh_f(c0);

    float a1v = tanh_f(acc1[0]);
    float i1v = sigf  (acc1[1]);
    float f1v = sigf  (acc1[2]);
    float o1v = sigf  (acc1[3]);
    c1 = i1v * a1v + f1v * c1;
    float hB = o1v * tanh_f(c1);

    // ---- publish h_{t+1}: coherent stores -> ack -> relaxed flag ----
    hstore2(wA_c, (__bf16)hA);
    hstore2(wB_c, (__bf16)hB);
    asm volatile("s_waitcnt vmcnt(0)" ::: "memory");
    if (l == 0)
      __hip_atomic_store(myflag, t + 2, __ATOMIC_RELAXED, __HIP_MEMORY_SCOPE_AGENT);

    // out stores: normal cached, off the critical path
    *opA = hA;
    *opB = hB;

    // ---- advance ----
    { const __bf16* tr = rd_c; rd_c = rd_n; rd_n = tr; }
    { __bf16* ta = wA_c; wA_c = wA_n; wA_n = ta; }
    { __bf16* tb = wB_c; wB_c = wB_n; wB_n = tb; }
    xp  += DD;
    xpf += DD;
    opA += HH;
    opB += HH;
  }
}

extern "C" void kernel_launch(void* const* d_in, const int* in_sizes, int n_in,
                              void* d_out, int out_size, void* d_ws, size_t ws_size,
                              hipStream_t stream) {
  const float* x   = (const float*)d_in[0];
  const float* Wc  = (const float*)d_in[1];
  const float* Wi  = (const float*)d_in[2];
  const float* Wf  = (const float*)d_in[3];
  const float* Wo  = (const float*)d_in[4];
  const float* Uc  = (const float*)d_in[5];
  const float* Ui  = (const float*)d_in[6];
  const float* Uf  = (const float*)d_in[7];
  const float* Uo  = (const float*)d_in[8];
  const float* bc  = (const float*)d_in[9];
  const float* bi  = (const float*)d_in[10];
  const float* bfv = (const float*)d_in[11];
  const float* bo  = (const float*)d_in[12];
  float* out = (float*)d_out;

  char* ws = (char*)d_ws;
  __bf16* hb0   = (__bf16*)ws;                     // 65536 B
  __bf16* hb1   = (__bf16*)(ws + 65536);           // 65536 B
  int*    flags = (int*)(ws + 131072);             // 256 * 4 B = 1 KiB
  __bf16* xbf   = (__bf16*)(ws + 132096);          // 64 MiB optional
  const size_t need_xbf = 132096ull + (size_t)BB * TT * DD * 2ull;
  int use_xbf = (ws_size >= need_xbf) ? 1 : 0;

  size_t zbytes = 132096;                          // hb0 + hb1 + flags
  if (zbytes > ws_size) zbytes = ws_size;
  hipMemsetAsync(d_ws, 0, zbytes, stream);

  lstm_fused<<<dim3(NBLK), dim3(NTHR), 0, stream>>>(
      x, Wc, Wi, Wf, Wo, Uc, Ui, Uf, Uo, bc, bi, bfv, bo,
      out, hb0, hb1, flags, xbf, use_xbf);
}